// Round 11
// baseline (145.169 us; speedup 1.0000x reference)
//
#include <hip/hip_runtime.h>
#include <stdint.h>

// Problem constants: B=4, T=2048, C=512, H=8, D=64
typedef __attribute__((ext_vector_type(8))) __bf16 bf16x8;
typedef __attribute__((ext_vector_type(4))) __bf16 bf16x4;
typedef __attribute__((ext_vector_type(2))) __bf16 bf16x2;
typedef __attribute__((ext_vector_type(4))) float f32x4;
typedef __attribute__((ext_vector_type(16))) float f32x16;
typedef __attribute__((ext_vector_type(4))) unsigned u32x4;
typedef __attribute__((ext_vector_type(2))) int i32x2;

__device__ __forceinline__ unsigned short f2bf(float f) {
  unsigned u = __float_as_uint(f);
  u += 0x7FFFu + ((u >> 16) & 1u);   // round-to-nearest-even
  return (unsigned short)(u >> 16);
}

__device__ __forceinline__ float exp2fast(float x) {
#if __has_builtin(__builtin_amdgcn_exp2f)
  return __builtin_amdgcn_exp2f(x);
#else
  return __expf(x * 0.6931471805599453f);
#endif
}

__device__ __forceinline__ void pl32swap(unsigned &a, unsigned &b) {
#if __has_builtin(__builtin_amdgcn_permlane32_swap)
  i32x2 r = __builtin_amdgcn_permlane32_swap((int)a, (int)b, false, false);
  a = (unsigned)r[0]; b = (unsigned)r[1];
#else
  asm volatile("v_permlane32_swap_b32 %0, %1" : "+v"(a), "+v"(b));
#endif
}

// rows r, r+8, r+16, r+24 get distinct octets (2-way max aliasing anywhere);
// swz8(r+32) == swz8(r)
__device__ __forceinline__ int swz8(int r) { return (r & 7) ^ ((r >> 3) & 3); }

__device__ __forceinline__ void gload16(const unsigned short* src, unsigned short* ldsdst) {
  __builtin_amdgcn_global_load_lds(
      (const __attribute__((address_space(1))) unsigned int*)src,
      (__attribute__((address_space(3))) unsigned int*)ldsdst, 16, 0, 0);
}

// Stage 8 rows x 64 bf16 (128B/row) into LDS tile (linear dest), with the
// global-source octet XOR-swizzled by swz8(row) so swizzled reads are
// bank-conflict-free (G21: swizzle source+read, dest stays linear).
__device__ __forceinline__ void stage8(const unsigned short* gbase, long long strideElems,
                                       unsigned short* ldsTile, int rowBase) {
  const int lane = threadIdx.x & 63;
  const int r = rowBase + (lane >> 3);
  const int oct = (lane & 7) ^ swz8(r);
  gload16(gbase + (long long)r * strideElems + oct * 8, ldsTile + rowBase * 64);
}

// ---------------- merged prep kernel ----------------

__global__ __launch_bounds__(256) void prep(const float* __restrict__ x,
                                            unsigned short* __restrict__ xb,
                                            const float* __restrict__ wq,
                                            unsigned short* __restrict__ wqt,
                                            const float* __restrict__ wp,
                                            unsigned short* __restrict__ wpt,
                                            const int* __restrict__ adj,
                                            unsigned long long* __restrict__ mb) {
  int blk = blockIdx.x;
  if (blk < 16384) {
    int tid = blk * 256 + threadIdx.x;
    int4 v = ((const int4*)adj)[tid];
    unsigned n = (v.x != 0 ? 1u : 0u) | (v.y != 0 ? 2u : 0u) |
                 (v.z != 0 ? 4u : 0u) | (v.w != 0 ? 8u : 0u);
    unsigned long long part = (unsigned long long)n << ((threadIdx.x & 15) * 4);
    part |= __shfl_xor(part, 1);
    part |= __shfl_xor(part, 2);
    part |= __shfl_xor(part, 4);
    part |= __shfl_xor(part, 8);
    if ((threadIdx.x & 15) == 0) mb[tid >> 4] = part;
    return;
  }
  blk -= 16384;
  if (blk < 4096) {
    int i = (blk * 256 + threadIdx.x) * 4;
    float4 v = *(const float4*)(x + i);
    ushort4 o;
    o.x = f2bf(v.x); o.y = f2bf(v.y); o.z = f2bf(v.z); o.w = f2bf(v.w);
    *(ushort4*)(xb + i) = o;
    return;
  }
  blk -= 4096;
  const float* w; unsigned short* wt; int N; int bx, by;
  if (blk < 768) { w = wq; wt = wqt; N = 1536; bx = blk & 15; by = blk >> 4; }
  else { blk -= 768; w = wp; wt = wpt; N = 512; bx = blk & 15; by = blk >> 4; }
  __shared__ float tile[32][33];
  int k0 = bx * 32, n0 = by * 32;
  int tx = threadIdx.x & 31, ty = threadIdx.x >> 5;
#pragma unroll
  for (int i = 0; i < 4; i++)
    tile[ty + i * 8][tx] = w[(long long)(k0 + ty + i * 8) * N + n0 + tx];
  __syncthreads();
#pragma unroll
  for (int i = 0; i < 4; i++)
    wt[(long long)(n0 + ty + i * 8) * 512 + k0 + tx] = f2bf(tile[tx][ty + i * 8]);
}

// ---------------- GEMM core: C[128x128] = A[M,512] * Wt[N,512]^T ----------------
// m97 structure: single-buffered 32KB LDS, per K-step:
// barrier; stage; vmcnt(0); barrier; compute.

__device__ __forceinline__ void gemm_core(const unsigned short* __restrict__ A,
                                          const unsigned short* __restrict__ Wt,
                                          unsigned short* Al, unsigned short* Bl,
                                          int m0, int n0, f32x4 acc[4][4]) {
  const int lane = threadIdx.x & 63;
  const int wid = threadIdx.x >> 6;
  const int c = lane & 15, g = lane >> 4;
  const int wm = wid >> 1, wn = wid & 1;
  const unsigned short* Ab = A + (long long)m0 * 512;
  const unsigned short* Bb = Wt + (long long)n0 * 512;

  for (int k0 = 0; k0 < 512; k0 += 64) {
    __syncthreads();
#pragma unroll
    for (int i = 0; i < 4; i++) stage8(Ab + k0, 512, Al, wid * 32 + i * 8);
#pragma unroll
    for (int i = 0; i < 4; i++) stage8(Bb + k0, 512, Bl, wid * 32 + i * 8);
    asm volatile("s_waitcnt vmcnt(0)" ::: "memory");
    __syncthreads();
#pragma unroll
    for (int kk = 0; kk < 2; kk++) {
      bf16x8 af[4], bfr[4];
#pragma unroll
      for (int mi = 0; mi < 4; mi++) {
        int row = wm * 64 + mi * 16 + c;
        af[mi] = *(const bf16x8*)&Al[row * 64 + (((kk << 2) | g) ^ swz8(row)) * 8];
      }
#pragma unroll
      for (int ni = 0; ni < 4; ni++) {
        int row = wn * 64 + ni * 16 + c;
        bfr[ni] = *(const bf16x8*)&Bl[row * 64 + (((kk << 2) | g) ^ swz8(row)) * 8];
      }
#pragma unroll
      for (int mi = 0; mi < 4; mi++)
#pragma unroll
        for (int ni = 0; ni < 4; ni++)
          acc[mi][ni] = __builtin_amdgcn_mfma_f32_16x16x32_bf16(af[mi], bfr[ni], acc[mi][ni], 0, 0, 0);
    }
  }
}

__global__ __launch_bounds__(256) void gemm_qkv(const unsigned short* __restrict__ xb,
                                                const unsigned short* __restrict__ wqt,
                                                const float* __restrict__ bqkv,
                                                unsigned short* __restrict__ qb,
                                                unsigned short* __restrict__ kb,
                                                unsigned short* __restrict__ vtb) {
  __shared__ __align__(16) unsigned short Al[128 * 64];
  __shared__ __align__(16) unsigned short Bl[128 * 64];
  f32x4 acc[4][4] = {};
  int m0 = blockIdx.x * 128, n0 = blockIdx.y * 128;
  gemm_core(xb, wqt, Al, Bl, m0, n0, acc);
  const int lane = threadIdx.x & 63;
  const int wid = threadIdx.x >> 6;
  const int c = lane & 15, g = lane >> 4;
  const int wm = wid >> 1, wn = wid & 1;
#pragma unroll
  for (int ni = 0; ni < 4; ni++) {
    int n = n0 + wn * 64 + ni * 16 + c;
    float bv = bqkv[n];
    int which = n >> 9;
    int h = (n & 511) >> 6, d = n & 63;
#pragma unroll
    for (int mi = 0; mi < 4; mi++) {
      int mbase = m0 + wm * 64 + mi * 16 + g * 4;   // 4 consecutive t, same batch
      int b = mbase >> 11, t0 = mbase & 2047;
      int bh = b * 8 + h;
      if (which == 2) {
        // V transposed [bh][d][t]: 4 consecutive t -> one 8B store
        ushort4 o;
        o.x = f2bf(acc[mi][ni][0] + bv); o.y = f2bf(acc[mi][ni][1] + bv);
        o.z = f2bf(acc[mi][ni][2] + bv); o.w = f2bf(acc[mi][ni][3] + bv);
        *(ushort4*)&vtb[((long long)bh * 64 + d) * 2048 + t0] = o;
      } else if (which == 0) {
#pragma unroll
        for (int j = 0; j < 4; j++)
          qb[(bh * 2048 + t0 + j) * 64 + d] = f2bf((acc[mi][ni][j] + bv) * 0.18033688011112042f);
      } else {
#pragma unroll
        for (int j = 0; j < 4; j++)
          kb[(bh * 2048 + t0 + j) * 64 + d] = f2bf(acc[mi][ni][j] + bv);
      }
    }
  }
}

__global__ __launch_bounds__(256) void gemm_proj(const unsigned short* __restrict__ yb,
                                                 const unsigned short* __restrict__ wpt,
                                                 const float* __restrict__ bproj,
                                                 float* __restrict__ out) {
  __shared__ __align__(16) unsigned short Al[128 * 64];
  __shared__ __align__(16) unsigned short Bl[128 * 64];
  f32x4 acc[4][4] = {};
  int m0 = blockIdx.x * 128, n0 = blockIdx.y * 128;
  gemm_core(yb, wpt, Al, Bl, m0, n0, acc);
  const int lane = threadIdx.x & 63;
  const int wid = threadIdx.x >> 6;
  const int c = lane & 15, g = lane >> 4;
  const int wm = wid >> 1, wn = wid & 1;
#pragma unroll
  for (int ni = 0; ni < 4; ni++) {
    int n = n0 + wn * 64 + ni * 16 + c;
    float bv = bproj[n];
#pragma unroll
    for (int mi = 0; mi < 4; mi++) {
      int mbase = m0 + wm * 64 + mi * 16 + g * 4;
#pragma unroll
      for (int j = 0; j < 4; j++)
        out[(long long)(mbase + j) * 512 + n] = acc[mi][ni][j] + bv;
    }
  }
}

// ---------------- flash attention: 8-wave in-block kv-split ----------------
// Grid 512 x 512 thr. bh = bid&31 (XCD-colocated K/V), qblock of 128 rows.
// Half-group h (waves 4h..4h+3) handles kv half [h*1024, +1024) for the same
// 128 q-rows; wave wq owns rows q0+wq*32..+31. Each half double-buffers its own
// K/V tiles (64 KB total -> 2 blocks/CU -> 16 waves/CU = 4/SIMD, 2x round 10's
// TLP: the measured limiter was the per-wave serial latency chain at 2/SIMD).
// No-max exp2 softmax => kv-half partials add exactly; combine through LDS at
// block end. Per-tile compute = round-10 structure (LUT C-seed, exp2, permlane
// register P, ones-MFMA denominator).
__global__ __launch_bounds__(512, 4) void attn(const unsigned short* __restrict__ qb,
                                               const unsigned short* __restrict__ kb,
                                               const unsigned short* __restrict__ vtb,
                                               const unsigned long long* __restrict__ mbits,
                                               unsigned short* __restrict__ yb) {
  __shared__ __align__(16) unsigned short Kl[2][2][64 * 64];  // [half][buf]
  __shared__ __align__(16) unsigned short Vl[2][2][64 * 64];
  __shared__ __align__(16) float lut4[16][4];   // nibble -> f32x4 seed (0 / -1e30)
  const int lane = threadIdx.x & 63;
  const int w = threadIdx.x >> 6;          // wave 0..7
  const int half = w >> 2;                 // kv half
  const int wq = w & 3;                    // q sub-block
  const int l31 = lane & 31, h5 = lane >> 5;
  const int sA = swz8(l31);
  const int bid = blockIdx.x;
  const int bh = bid & 31;                 // xcd = bid%8 = bh%8 -> K/V L2-resident
  const int q0 = (bid >> 5) * 128;
  const int b = bh >> 3, h = bh & 7;
  const int qglob = q0 + wq * 32 + l31;
  const int kvbase = half * 1024;

  if (threadIdx.x < 16) {
    int n = threadIdx.x;
#pragma unroll
    for (int j = 0; j < 4; j++) lut4[n][j] = ((n >> j) & 1) ? 0.0f : -1e30f;
  }

  const unsigned short* qptr = qb + ((long long)bh * 2048 + qglob) * 64;
  bf16x8 qf[4];
#pragma unroll
  for (int cc = 0; cc < 4; cc++) qf[cc] = *(const bf16x8*)(qptr + cc * 16 + h5 * 8);

  const unsigned long long* mrow =
      mbits + ((long long)b * 2048 + qglob) * 32 + half * 16;

  // per-lane staging sources (per-tile increments: K +4096 elems, V^T +64)
  const int ln8 = lane >> 3, o8 = lane & 7;
  const int rA = wq * 16 + ln8, rB = rA + 8;
  const unsigned short* ksA = kb + (long long)bh * 2048 * 64 + (long long)(kvbase + rA) * 64 + (o8 ^ swz8(rA)) * 8;
  const unsigned short* ksB = kb + (long long)bh * 2048 * 64 + (long long)(kvbase + rB) * 64 + (o8 ^ swz8(rB)) * 8;
  const unsigned short* vsA = vtb + (long long)bh * 64 * 2048 + (long long)rA * 2048 + kvbase + (o8 ^ swz8(rA)) * 8;
  const unsigned short* vsB = vtb + (long long)bh * 64 * 2048 + (long long)rB * 2048 + kvbase + (o8 ^ swz8(rB)) * 8;
  const int ldA = wq * 16 * 64, ldB = (wq * 16 + 8) * 64;   // wave-uniform LDS dests

  unsigned short* K0 = &Kl[half][0][0];
  unsigned short* K1 = &Kl[half][1][0];
  unsigned short* V0 = &Vl[half][0][0];
  unsigned short* V1 = &Vl[half][1][0];

  // per-lane fragment column offsets
  const int uo0 = ((0 + h5) ^ sA) * 8, uo1 = ((2 + h5) ^ sA) * 8;
  const int uo2 = ((4 + h5) ^ sA) * 8, uo3 = ((6 + h5) ^ sA) * 8;

  __bf16 onebf = (__bf16)1.0f;
  bf16x8 ones = {onebf, onebf, onebf, onebf, onebf, onebf, onebf, onebf};

  f32x16 accO0 = {0,0,0,0, 0,0,0,0, 0,0,0,0, 0,0,0,0};
  f32x16 accO1 = {0,0,0,0, 0,0,0,0, 0,0,0,0, 0,0,0,0};
  f32x16 lacc  = {0,0,0,0, 0,0,0,0, 0,0,0,0, 0,0,0,0};

#define STAGE_T(KB, VB) do {                   \
    gload16(ksA, (KB) + ldA);                  \
    gload16(ksB, (KB) + ldB);                  \
    gload16(vsA, (VB) + ldA);                  \
    gload16(vsB, (VB) + ldB);                  \
    ksA += 4096; ksB += 4096; vsA += 64; vsB += 64; } while (0)

  auto COMPUTE = [&](const unsigned short* Kb, const unsigned short* Vb,
                     unsigned long long mwv) {
    // seed S^T accumulators from the nibble LUT
    // C reg r of tile ot: kv = ot*32 + (r&3) + 8*(r>>2) + 4*h5
    unsigned lo = (unsigned)mwv, hi = (unsigned)(mwv >> 32);
    f32x16 st0, st1;
#pragma unroll
    for (int j = 0; j < 4; j++) {
      f32x4 s0 = *(const f32x4*)lut4[(lo >> (8 * j + 4 * h5)) & 0xF];
      f32x4 s1 = *(const f32x4*)lut4[(hi >> (8 * j + 4 * h5)) & 0xF];
#pragma unroll
      for (int i = 0; i < 4; i++) { st0[4 * j + i] = s0[i]; st1[4 * j + i] = s1[i]; }
    }
    // S^T = K * Q^T
    __builtin_amdgcn_s_setprio(1);
#pragma unroll
    for (int cc = 0; cc < 4; cc++) {
      const int u = (cc == 0) ? uo0 : (cc == 1) ? uo1 : (cc == 2) ? uo2 : uo3;
      bf16x8 kf0 = *(const bf16x8*)&Kb[l31 * 64 + u];
      bf16x8 kf1 = *(const bf16x8*)&Kb[(32 + l31) * 64 + u];
      st0 = __builtin_amdgcn_mfma_f32_32x32x16_bf16(kf0, qf[cc], st0, 0, 0, 0);
      st1 = __builtin_amdgcn_mfma_f32_32x32x16_bf16(kf1, qf[cc], st1, 0, 0, 0);
    }
    __builtin_amdgcn_s_setprio(0);
    // exp2 softmax (masked entries hit exp2(-1e30) = 0), pack bf16
    unsigned pd[2][8];
#pragma unroll
    for (int m = 0; m < 8; m++) {
      float p0 = exp2fast(st0[2 * m]);
      float p1 = exp2fast(st0[2 * m + 1]);
      float p2 = exp2fast(st1[2 * m]);
      float p3 = exp2fast(st1[2 * m + 1]);
      bf16x2 v0 = {(__bf16)p0, (__bf16)p1};
      bf16x2 v1 = {(__bf16)p2, (__bf16)p3};
      pd[0][m] = __builtin_bit_cast(unsigned, v0);
      pd[1][m] = __builtin_bit_cast(unsigned, v1);
    }
    // PV B-fragments: l <-> l+32 dword exchange
#pragma unroll
    for (int ot = 0; ot < 2; ot++)
#pragma unroll
      for (int hc = 0; hc < 2; hc++) {
        pl32swap(pd[ot][4 * hc + 0], pd[ot][4 * hc + 2]);
        pl32swap(pd[ot][4 * hc + 1], pd[ot][4 * hc + 3]);
      }
    // O^T += V^T * P^T ; row-sum denominator via ones-A MFMA
    __builtin_amdgcn_s_setprio(1);
#pragma unroll
    for (int cc = 0; cc < 4; cc++) {
      u32x4 pu = {pd[cc >> 1][4 * (cc & 1) + 0], pd[cc >> 1][4 * (cc & 1) + 1],
                  pd[cc >> 1][4 * (cc & 1) + 2], pd[cc >> 1][4 * (cc & 1) + 3]};
      bf16x8 pf = __builtin_bit_cast(bf16x8, pu);
      const int u = (cc == 0) ? uo0 : (cc == 1) ? uo1 : (cc == 2) ? uo2 : uo3;
      bf16x8 vf0 = *(const bf16x8*)&Vb[l31 * 64 + u];
      bf16x8 vf1 = *(const bf16x8*)&Vb[(32 + l31) * 64 + u];
      accO0 = __builtin_amdgcn_mfma_f32_32x32x16_bf16(vf0, pf, accO0, 0, 0, 0);
      accO1 = __builtin_amdgcn_mfma_f32_32x32x16_bf16(vf1, pf, accO1, 0, 0, 0);
      lacc  = __builtin_amdgcn_mfma_f32_32x32x16_bf16(ones, pf, lacc, 0, 0, 0);
    }
    __builtin_amdgcn_s_setprio(0);
  };

#define TILE_SYNC do {                                     \
    asm volatile("s_waitcnt lgkmcnt(0)" ::: "memory");     \
    asm volatile("s_waitcnt vmcnt(0)" ::: "memory");       \
    __builtin_amdgcn_s_barrier(); } while (0)

  // prologue: stage tile 0 (also makes LUT init visible via the barrier)
  unsigned long long mA, mB;
  STAGE_T(K0, V0); mA = mrow[0];
  TILE_SYNC;

  for (int k = 0; k < 7; ++k) {   // tiles 0..13
    STAGE_T(K1, V1); mB = mrow[2 * k + 1];
    COMPUTE(K0, V0, mA);
    TILE_SYNC;
    STAGE_T(K0, V0); mA = mrow[2 * k + 2];
    COMPUTE(K1, V1, mB);
    TILE_SYNC;
  }
  // tiles 14, 15
  STAGE_T(K1, V1); mB = mrow[15];
  COMPUTE(K0, V0, mA);
  TILE_SYNC;
  COMPUTE(K1, V1, mB);

#undef TILE_SYNC
#undef STAGE_T

  // ---- kv-half combine via LDS (reuse K/V staging space) ----
  __syncthreads();
  float* xch = (float*)&Kl[0][0][0];   // 64KB area; need 256 lanes * 36 floats = 36KB
  if (half == 1) {
    float* dst = xch + (wq * 64 + lane) * 36;
#pragma unroll
    for (int m = 0; m < 4; m++) {
      f32x4 a = {accO0[4 * m + 0], accO0[4 * m + 1], accO0[4 * m + 2], accO0[4 * m + 3]};
      f32x4 c = {accO1[4 * m + 0], accO1[4 * m + 1], accO1[4 * m + 2], accO1[4 * m + 3]};
      *(f32x4*)(dst + 4 * m) = a;
      *(f32x4*)(dst + 16 + 4 * m) = c;
    }
    dst[32] = lacc[0];
  }
  __syncthreads();
  if (half == 0) {
    const float* src = xch + (wq * 64 + lane) * 36;
    float linv = 1.0f / (lacc[0] + src[32]);
    unsigned short* yrow = yb + ((long long)(b * 2048 + qglob)) * 512 + h * 64;
#pragma unroll
    for (int m = 0; m < 4; m++) {
      f32x4 a = *(const f32x4*)(src + 4 * m);
      f32x4 c = *(const f32x4*)(src + 16 + 4 * m);
      int d0 = 8 * m + 4 * h5;
      bf16x4 o0 = {(__bf16)((accO0[4 * m + 0] + a[0]) * linv),
                   (__bf16)((accO0[4 * m + 1] + a[1]) * linv),
                   (__bf16)((accO0[4 * m + 2] + a[2]) * linv),
                   (__bf16)((accO0[4 * m + 3] + a[3]) * linv)};
      bf16x4 o1 = {(__bf16)((accO1[4 * m + 0] + c[0]) * linv),
                   (__bf16)((accO1[4 * m + 1] + c[1]) * linv),
                   (__bf16)((accO1[4 * m + 2] + c[2]) * linv),
                   (__bf16)((accO1[4 * m + 3] + c[3]) * linv)};
      *(bf16x4*)&yrow[d0] = o0;
      *(bf16x4*)&yrow[32 + d0] = o1;
    }
  }
}

// ---------------- launcher ----------------

extern "C" void kernel_launch(void* const* d_in, const int* in_sizes, int n_in,
                              void* d_out, int out_size, void* d_ws, size_t ws_size,
                              hipStream_t stream) {
  const float* x      = (const float*)d_in[0];
  const int*   adj    = (const int*)d_in[1];
  const float* w_qkv  = (const float*)d_in[2];
  const float* b_qkv  = (const float*)d_in[3];
  const float* w_proj = (const float*)d_in[4];
  const float* b_proj = (const float*)d_in[5];
  float* out = (float*)d_out;

  char* ws = (char*)d_ws;
  unsigned short* xb  = (unsigned short*)(ws);              // 8.4MB  (reused as yb)
  unsigned short* qb  = (unsigned short*)(ws + 8388608);    // 8.4MB
  unsigned short* kbf = (unsigned short*)(ws + 16777216);   // 8.4MB
  unsigned short* vtb = (unsigned short*)(ws + 25165824);   // 8.4MB
  unsigned short* wqt = (unsigned short*)(ws + 33554432);   // 1.57MB
  unsigned short* wpt = (unsigned short*)(ws + 35127296);   // 0.52MB
  unsigned long long* mb = (unsigned long long*)(ws + 35651584); // 2MB  (end 37.75MB)
  unsigned short* yb = xb;  // x is dead after gemm_qkv

  prep<<<dim3(21504), dim3(256), 0, stream>>>(x, xb, w_qkv, wqt, w_proj, wpt, adj, mb);
  gemm_qkv<<<dim3(64, 12), dim3(256), 0, stream>>>(xb, wqt, b_qkv, qb, kbf, vtb);
  attn<<<dim3(512), dim3(512), 0, stream>>>(qb, kbf, vtb, mb, yb);
  gemm_proj<<<dim3(64, 4), dim3(256), 0, stream>>>(yb, wpt, b_proj, out);
}

// Round 12
// 115.244 us; speedup vs baseline: 1.2597x; 1.2597x over previous
//
#include <hip/hip_runtime.h>
#include <stdint.h>

// Problem constants: B=4, T=2048, C=512, H=8, D=64
typedef __attribute__((ext_vector_type(8))) __bf16 bf16x8;
typedef __attribute__((ext_vector_type(4))) __bf16 bf16x4;
typedef __attribute__((ext_vector_type(2))) __bf16 bf16x2;
typedef __attribute__((ext_vector_type(4))) float f32x4;
typedef __attribute__((ext_vector_type(16))) float f32x16;
typedef __attribute__((ext_vector_type(4))) unsigned u32x4;
typedef __attribute__((ext_vector_type(2))) int i32x2;

__device__ __forceinline__ unsigned short f2bf(float f) {
  unsigned u = __float_as_uint(f);
  u += 0x7FFFu + ((u >> 16) & 1u);   // round-to-nearest-even
  return (unsigned short)(u >> 16);
}

__device__ __forceinline__ float exp2fast(float x) {
#if __has_builtin(__builtin_amdgcn_exp2f)
  return __builtin_amdgcn_exp2f(x);
#else
  return __expf(x * 0.6931471805599453f);
#endif
}

__device__ __forceinline__ void pl32swap(unsigned &a, unsigned &b) {
#if __has_builtin(__builtin_amdgcn_permlane32_swap)
  i32x2 r = __builtin_amdgcn_permlane32_swap((int)a, (int)b, false, false);
  a = (unsigned)r[0]; b = (unsigned)r[1];
#else
  asm volatile("v_permlane32_swap_b32 %0, %1" : "+v"(a), "+v"(b));
#endif
}

// rows r, r+8, r+16, r+24 get distinct octets (2-way max aliasing anywhere);
// swz8(r+32) == swz8(r)
__device__ __forceinline__ int swz8(int r) { return (r & 7) ^ ((r >> 3) & 3); }

__device__ __forceinline__ void gload16(const unsigned short* src, unsigned short* ldsdst) {
  __builtin_amdgcn_global_load_lds(
      (const __attribute__((address_space(1))) unsigned int*)src,
      (__attribute__((address_space(3))) unsigned int*)ldsdst, 16, 0, 0);
}

// Stage 8 rows x 64 bf16 (128B/row) into LDS tile (linear dest), with the
// global-source octet XOR-swizzled by swz8(row) so swizzled reads are
// bank-conflict-free (G21: swizzle source+read, dest stays linear).
__device__ __forceinline__ void stage8(const unsigned short* gbase, long long strideElems,
                                       unsigned short* ldsTile, int rowBase) {
  const int lane = threadIdx.x & 63;
  const int r = rowBase + (lane >> 3);
  const int oct = (lane & 7) ^ swz8(r);
  gload16(gbase + (long long)r * strideElems + oct * 8, ldsTile + rowBase * 64);
}

// ---------------- merged prep kernel ----------------

__global__ __launch_bounds__(256) void prep(const float* __restrict__ x,
                                            unsigned short* __restrict__ xb,
                                            const float* __restrict__ wq,
                                            unsigned short* __restrict__ wqt,
                                            const float* __restrict__ wp,
                                            unsigned short* __restrict__ wpt,
                                            const int* __restrict__ adj,
                                            unsigned long long* __restrict__ mb) {
  int blk = blockIdx.x;
  if (blk < 16384) {
    int tid = blk * 256 + threadIdx.x;
    int4 v = ((const int4*)adj)[tid];
    unsigned n = (v.x != 0 ? 1u : 0u) | (v.y != 0 ? 2u : 0u) |
                 (v.z != 0 ? 4u : 0u) | (v.w != 0 ? 8u : 0u);
    unsigned long long part = (unsigned long long)n << ((threadIdx.x & 15) * 4);
    part |= __shfl_xor(part, 1);
    part |= __shfl_xor(part, 2);
    part |= __shfl_xor(part, 4);
    part |= __shfl_xor(part, 8);
    if ((threadIdx.x & 15) == 0) mb[tid >> 4] = part;
    return;
  }
  blk -= 16384;
  if (blk < 4096) {
    int i = (blk * 256 + threadIdx.x) * 4;
    float4 v = *(const float4*)(x + i);
    ushort4 o;
    o.x = f2bf(v.x); o.y = f2bf(v.y); o.z = f2bf(v.z); o.w = f2bf(v.w);
    *(ushort4*)(xb + i) = o;
    return;
  }
  blk -= 4096;
  const float* w; unsigned short* wt; int N; int bx, by;
  if (blk < 768) { w = wq; wt = wqt; N = 1536; bx = blk & 15; by = blk >> 4; }
  else { blk -= 768; w = wp; wt = wpt; N = 512; bx = blk & 15; by = blk >> 4; }
  __shared__ float tile[32][33];
  int k0 = bx * 32, n0 = by * 32;
  int tx = threadIdx.x & 31, ty = threadIdx.x >> 5;
#pragma unroll
  for (int i = 0; i < 4; i++)
    tile[ty + i * 8][tx] = w[(long long)(k0 + ty + i * 8) * N + n0 + tx];
  __syncthreads();
#pragma unroll
  for (int i = 0; i < 4; i++)
    wt[(long long)(n0 + ty + i * 8) * 512 + k0 + tx] = f2bf(tile[tx][ty + i * 8]);
}

// ---------------- GEMM core: C[128x128] = A[M,512] * Wt[N,512]^T ----------------
// m97 structure: single-buffered 32KB LDS, per K-step:
// barrier; stage; vmcnt(0); barrier; compute.

__device__ __forceinline__ void gemm_core(const unsigned short* __restrict__ A,
                                          const unsigned short* __restrict__ Wt,
                                          unsigned short* Al, unsigned short* Bl,
                                          int m0, int n0, f32x4 acc[4][4]) {
  const int lane = threadIdx.x & 63;
  const int wid = threadIdx.x >> 6;
  const int c = lane & 15, g = lane >> 4;
  const int wm = wid >> 1, wn = wid & 1;
  const unsigned short* Ab = A + (long long)m0 * 512;
  const unsigned short* Bb = Wt + (long long)n0 * 512;

  for (int k0 = 0; k0 < 512; k0 += 64) {
    __syncthreads();
#pragma unroll
    for (int i = 0; i < 4; i++) stage8(Ab + k0, 512, Al, wid * 32 + i * 8);
#pragma unroll
    for (int i = 0; i < 4; i++) stage8(Bb + k0, 512, Bl, wid * 32 + i * 8);
    asm volatile("s_waitcnt vmcnt(0)" ::: "memory");
    __syncthreads();
#pragma unroll
    for (int kk = 0; kk < 2; kk++) {
      bf16x8 af[4], bfr[4];
#pragma unroll
      for (int mi = 0; mi < 4; mi++) {
        int row = wm * 64 + mi * 16 + c;
        af[mi] = *(const bf16x8*)&Al[row * 64 + (((kk << 2) | g) ^ swz8(row)) * 8];
      }
#pragma unroll
      for (int ni = 0; ni < 4; ni++) {
        int row = wn * 64 + ni * 16 + c;
        bfr[ni] = *(const bf16x8*)&Bl[row * 64 + (((kk << 2) | g) ^ swz8(row)) * 8];
      }
#pragma unroll
      for (int mi = 0; mi < 4; mi++)
#pragma unroll
        for (int ni = 0; ni < 4; ni++)
          acc[mi][ni] = __builtin_amdgcn_mfma_f32_16x16x32_bf16(af[mi], bfr[ni], acc[mi][ni], 0, 0, 0);
    }
  }
}

__global__ __launch_bounds__(256) void gemm_qkv(const unsigned short* __restrict__ xb,
                                                const unsigned short* __restrict__ wqt,
                                                const float* __restrict__ bqkv,
                                                unsigned short* __restrict__ qb,
                                                unsigned short* __restrict__ kb,
                                                unsigned short* __restrict__ vtb) {
  __shared__ __align__(16) unsigned short Al[128 * 64];
  __shared__ __align__(16) unsigned short Bl[128 * 64];
  f32x4 acc[4][4] = {};
  int m0 = blockIdx.x * 128, n0 = blockIdx.y * 128;
  gemm_core(xb, wqt, Al, Bl, m0, n0, acc);
  const int lane = threadIdx.x & 63;
  const int wid = threadIdx.x >> 6;
  const int c = lane & 15, g = lane >> 4;
  const int wm = wid >> 1, wn = wid & 1;
#pragma unroll
  for (int ni = 0; ni < 4; ni++) {
    int n = n0 + wn * 64 + ni * 16 + c;
    float bv = bqkv[n];
    int which = n >> 9;
    int h = (n & 511) >> 6, d = n & 63;
#pragma unroll
    for (int mi = 0; mi < 4; mi++) {
      int mbase = m0 + wm * 64 + mi * 16 + g * 4;   // 4 consecutive t, same batch
      int b = mbase >> 11, t0 = mbase & 2047;
      int bh = b * 8 + h;
      if (which == 2) {
        // V transposed [bh][d][t]: 4 consecutive t -> one 8B store
        ushort4 o;
        o.x = f2bf(acc[mi][ni][0] + bv); o.y = f2bf(acc[mi][ni][1] + bv);
        o.z = f2bf(acc[mi][ni][2] + bv); o.w = f2bf(acc[mi][ni][3] + bv);
        *(ushort4*)&vtb[((long long)bh * 64 + d) * 2048 + t0] = o;
      } else if (which == 0) {
#pragma unroll
        for (int j = 0; j < 4; j++)
          qb[(bh * 2048 + t0 + j) * 64 + d] = f2bf((acc[mi][ni][j] + bv) * 0.18033688011112042f);
      } else {
#pragma unroll
        for (int j = 0; j < 4; j++)
          kb[(bh * 2048 + t0 + j) * 64 + d] = f2bf(acc[mi][ni][j] + bv);
      }
    }
  }
}

__global__ __launch_bounds__(256) void gemm_proj(const unsigned short* __restrict__ yb,
                                                 const unsigned short* __restrict__ wpt,
                                                 const float* __restrict__ bproj,
                                                 float* __restrict__ out) {
  __shared__ __align__(16) unsigned short Al[128 * 64];
  __shared__ __align__(16) unsigned short Bl[128 * 64];
  f32x4 acc[4][4] = {};
  int m0 = blockIdx.x * 128, n0 = blockIdx.y * 128;
  gemm_core(yb, wpt, Al, Bl, m0, n0, acc);
  const int lane = threadIdx.x & 63;
  const int wid = threadIdx.x >> 6;
  const int c = lane & 15, g = lane >> 4;
  const int wm = wid >> 1, wn = wid & 1;
#pragma unroll
  for (int ni = 0; ni < 4; ni++) {
    int n = n0 + wn * 64 + ni * 16 + c;
    float bv = bproj[n];
#pragma unroll
    for (int mi = 0; mi < 4; mi++) {
      int mbase = m0 + wm * 64 + mi * 16 + g * 4;
#pragma unroll
      for (int j = 0; j < 4; j++)
        out[(long long)(mbase + j) * 512 + n] = acc[mi][ni][j] + bv;
    }
  }
}

// ---------------- flash attention: 4-wave wave-pair kv-split ----------------
// Grid 1024 x 256 thr. bh = bid&31 (XCD-colocated K/V), q-block of 64 rows.
// Waves {0,1} process kv half 0, waves {2,3} kv half 1 for the SAME 64 q-rows
// (wave wq owns rows q0+wq*32..+31). Each half single-buffers its K/V tile
// (16 KB x 2 halves + lut + xl ~= 33.3 KB -> 4 blocks/CU = 16 waves/CU =
// 4 waves/SIMD, 2x round-10 TLP; the measured limiter was per-wave serial
// latency at 2/SIMD). Per-tile sync = proven m97 pattern (barrier; stage;
// vmcnt(0); barrier; compute) - drains overlap across the 4 resident blocks.
// Register diet for the 128-VGPR cap: no lacc MFMA (VALU lsum + one final
// shfl), st0/st1 serialized, 8 persistent staging pointers. No-max exp2
// softmax => kv-half partials add exactly; one-barrier LDS combine (each half
// keeps its d-range, donates the other).
__global__ __launch_bounds__(256, 4) void attn(const unsigned short* __restrict__ qb,
                                               const unsigned short* __restrict__ kb,
                                               const unsigned short* __restrict__ vtb,
                                               const unsigned long long* __restrict__ mbits,
                                               unsigned short* __restrict__ yb) {
  __shared__ __align__(16) unsigned short Kl[2][64 * 64];  // [half]
  __shared__ __align__(16) unsigned short Vl[2][64 * 64];
  __shared__ __align__(16) float lut4[16][4];   // nibble -> f32x4 seed (0 / -1e30)
  __shared__ float xl[2][128];                  // per-half row-sum exchange
  const int lane = threadIdx.x & 63;
  const int w = threadIdx.x >> 6;          // wave 0..3
  const int half = w >> 1;                 // kv half
  const int wq = w & 1;                    // q sub-block (32 rows)
  const int l31 = lane & 31, h5 = lane >> 5;
  const int sA = swz8(l31);
  const int bid = blockIdx.x;
  const int bh = bid & 31;                 // xcd = bid%8 = bh%8 -> K/V L2-resident
  const int q0 = (bid >> 5) * 64;
  const int b = bh >> 3, h = bh & 7;
  const int qglob = q0 + wq * 32 + l31;

  if (threadIdx.x < 16) {
    int n = threadIdx.x;
#pragma unroll
    for (int j = 0; j < 4; j++) lut4[n][j] = ((n >> j) & 1) ? 0.0f : -1e30f;
  }

  const unsigned short* qptr = qb + ((long long)bh * 2048 + qglob) * 64;
  bf16x8 qf[4];
#pragma unroll
  for (int cc = 0; cc < 4; cc++) qf[cc] = *(const bf16x8*)(qptr + cc * 16 + h5 * 8);

  const unsigned long long* mrow =
      mbits + ((long long)b * 2048 + qglob) * 32 + half * 16;

  // persistent per-lane staging pointers: wave stages tile rows wq*32+8i+ln8
  // (i=0..3) for both K (row=kv) and V^T (row=d); octet = o8 ^ swz8(row_in_tile)
  // = o8 ^ ln8 ^ (i&3). K advances +4096 elems/tile, V +64.
  const int ln8 = lane >> 3, o8 = lane & 7;
  const unsigned short* kp0;
  const unsigned short* kp1;
  const unsigned short* kp2;
  const unsigned short* kp3;
  const unsigned short* vp0;
  const unsigned short* vp1;
  const unsigned short* vp2;
  const unsigned short* vp3;
  {
    const long long kb0 = (long long)bh * 2048 * 64 + (long long)(half * 1024) * 64;
    const long long vb0 = (long long)bh * 64 * 2048 + half * 1024;
    const int rr = wq * 32 + ln8;
    kp0 = kb + kb0 + (rr + 0) * 64 + ((o8 ^ ln8 ^ 0)) * 8;
    kp1 = kb + kb0 + (rr + 8) * 64 + ((o8 ^ ln8 ^ 1)) * 8;
    kp2 = kb + kb0 + (rr + 16) * 64 + ((o8 ^ ln8 ^ 2)) * 8;
    kp3 = kb + kb0 + (rr + 24) * 64 + ((o8 ^ ln8 ^ 3)) * 8;
    vp0 = vtb + vb0 + (long long)(rr + 0) * 2048 + ((o8 ^ ln8 ^ 0)) * 8;
    vp1 = vtb + vb0 + (long long)(rr + 8) * 2048 + ((o8 ^ ln8 ^ 1)) * 8;
    vp2 = vtb + vb0 + (long long)(rr + 16) * 2048 + ((o8 ^ ln8 ^ 2)) * 8;
    vp3 = vtb + vb0 + (long long)(rr + 24) * 2048 + ((o8 ^ ln8 ^ 3)) * 8;
  }
  unsigned short* Kd = &Kl[half][0] + wq * 32 * 64;   // wave-uniform LDS dests
  unsigned short* Vd = &Vl[half][0] + wq * 32 * 64;

  const unsigned short* Kb = &Kl[half][0];
  const unsigned short* Vb = &Vl[half][0];

  // per-lane fragment column offsets
  const int uo0 = ((0 + h5) ^ sA) * 8, uo1 = ((2 + h5) ^ sA) * 8;
  const int uo2 = ((4 + h5) ^ sA) * 8, uo3 = ((6 + h5) ^ sA) * 8;

  f32x16 accO0 = {0,0,0,0, 0,0,0,0, 0,0,0,0, 0,0,0,0};
  f32x16 accO1 = {0,0,0,0, 0,0,0,0, 0,0,0,0, 0,0,0,0};
  float lsum = 0.0f;

  for (int t = 0; t < 16; ++t) {
    __syncthreads();                       // prior compute's LDS reads done
    gload16(kp0, Kd);        gload16(kp1, Kd + 8 * 64);
    gload16(kp2, Kd + 16 * 64); gload16(kp3, Kd + 24 * 64);
    gload16(vp0, Vd);        gload16(vp1, Vd + 8 * 64);
    gload16(vp2, Vd + 16 * 64); gload16(vp3, Vd + 24 * 64);
    kp0 += 4096; kp1 += 4096; kp2 += 4096; kp3 += 4096;
    vp0 += 64; vp1 += 64; vp2 += 64; vp3 += 64;
    unsigned long long mw = mrow[t];
    asm volatile("s_waitcnt vmcnt(0)" ::: "memory");
    __syncthreads();

    unsigned lo = (unsigned)mw, hi = (unsigned)(mw >> 32);
    unsigned pd[2][8];
    // ---- st0: kv 0..31 (serialized vs st1 to cap live registers) ----
    {
      f32x16 st;
#pragma unroll
      for (int j = 0; j < 4; j++) {
        f32x4 s = *(const f32x4*)lut4[(lo >> (8 * j + 4 * h5)) & 0xF];
#pragma unroll
        for (int i = 0; i < 4; i++) st[4 * j + i] = s[i];
      }
      __builtin_amdgcn_s_setprio(1);
#pragma unroll
      for (int cc = 0; cc < 4; cc++) {
        const int u = (cc == 0) ? uo0 : (cc == 1) ? uo1 : (cc == 2) ? uo2 : uo3;
        bf16x8 kf = *(const bf16x8*)&Kb[l31 * 64 + u];
        st = __builtin_amdgcn_mfma_f32_32x32x16_bf16(kf, qf[cc], st, 0, 0, 0);
      }
      __builtin_amdgcn_s_setprio(0);
#pragma unroll
      for (int m = 0; m < 8; m++) {
        float p0 = exp2fast(st[2 * m]);
        float p1 = exp2fast(st[2 * m + 1]);
        lsum += (p0 + p1);
        bf16x2 v0 = {(__bf16)p0, (__bf16)p1};
        pd[0][m] = __builtin_bit_cast(unsigned, v0);
      }
    }
    // ---- st1: kv 32..63 ----
    {
      f32x16 st;
#pragma unroll
      for (int j = 0; j < 4; j++) {
        f32x4 s = *(const f32x4*)lut4[(hi >> (8 * j + 4 * h5)) & 0xF];
#pragma unroll
        for (int i = 0; i < 4; i++) st[4 * j + i] = s[i];
      }
      __builtin_amdgcn_s_setprio(1);
#pragma unroll
      for (int cc = 0; cc < 4; cc++) {
        const int u = (cc == 0) ? uo0 : (cc == 1) ? uo1 : (cc == 2) ? uo2 : uo3;
        bf16x8 kf = *(const bf16x8*)&Kb[(32 + l31) * 64 + u];
        st = __builtin_amdgcn_mfma_f32_32x32x16_bf16(kf, qf[cc], st, 0, 0, 0);
      }
      __builtin_amdgcn_s_setprio(0);
#pragma unroll
      for (int m = 0; m < 8; m++) {
        float p0 = exp2fast(st[2 * m]);
        float p1 = exp2fast(st[2 * m + 1]);
        lsum += (p0 + p1);
        bf16x2 v0 = {(__bf16)p0, (__bf16)p1};
        pd[1][m] = __builtin_bit_cast(unsigned, v0);
      }
    }
    // ---- PV B-fragments: l <-> l+32 dword exchange ----
#pragma unroll
    for (int ot = 0; ot < 2; ot++)
#pragma unroll
      for (int hc = 0; hc < 2; hc++) {
        pl32swap(pd[ot][4 * hc + 0], pd[ot][4 * hc + 2]);
        pl32swap(pd[ot][4 * hc + 1], pd[ot][4 * hc + 3]);
      }
    // ---- O^T += V^T * P^T ----
    __builtin_amdgcn_s_setprio(1);
#pragma unroll
    for (int cc = 0; cc < 4; cc++) {
      u32x4 pu = {pd[cc >> 1][4 * (cc & 1) + 0], pd[cc >> 1][4 * (cc & 1) + 1],
                  pd[cc >> 1][4 * (cc & 1) + 2], pd[cc >> 1][4 * (cc & 1) + 3]};
      bf16x8 pf = __builtin_bit_cast(bf16x8, pu);
      const int u = (cc == 0) ? uo0 : (cc == 1) ? uo1 : (cc == 2) ? uo2 : uo3;
      bf16x8 vf0 = *(const bf16x8*)&Vb[l31 * 64 + u];
      bf16x8 vf1 = *(const bf16x8*)&Vb[(32 + l31) * 64 + u];
      accO0 = __builtin_amdgcn_mfma_f32_32x32x16_bf16(vf0, pf, accO0, 0, 0, 0);
      accO1 = __builtin_amdgcn_mfma_f32_32x32x16_bf16(vf1, pf, accO1, 0, 0, 0);
    }
    __builtin_amdgcn_s_setprio(0);
  }

  // full row-sum for this half (lane's lsum covers its h5 kv-subset)
  float lh = lsum + __shfl_xor(lsum, 32);

  // ---- cross-half combine: each half keeps its d-range, donates the other ----
  __syncthreads();                                  // last compute's reads done
  float* xch = (float*)&Kl[0][0];                   // 256 x 16 f32 = 16 KB
  {
    float* dst = xch + (w * 64 + lane) * 16;
    f32x16 give = half ? accO0 : accO1;
#pragma unroll
    for (int m = 0; m < 4; m++)
      *(f32x4*)(dst + 4 * m) = f32x4{give[4 * m + 0], give[4 * m + 1],
                                     give[4 * m + 2], give[4 * m + 3]};
    xl[half][wq * 64 + lane] = lh;
  }
  __syncthreads();
  {
    const float* src = xch + (((half ^ 1) * 2 + wq) * 64 + lane) * 16;
    float linv = 1.0f / (lh + xl[half ^ 1][wq * 64 + lane]);
    f32x16 keep = half ? accO1 : accO0;
    unsigned short* yrow = yb + ((long long)(b * 2048 + qglob)) * 512 + h * 64 + half * 32;
#pragma unroll
    for (int m = 0; m < 4; m++) {
      f32x4 a = *(const f32x4*)(src + 4 * m);
      int d0 = 8 * m + 4 * h5;
      bf16x4 o = {(__bf16)((keep[4 * m + 0] + a[0]) * linv),
                  (__bf16)((keep[4 * m + 1] + a[1]) * linv),
                  (__bf16)((keep[4 * m + 2] + a[2]) * linv),
                  (__bf16)((keep[4 * m + 3] + a[3]) * linv)};
      *(bf16x4*)&yrow[d0] = o;
    }
  }
}

// ---------------- launcher ----------------

extern "C" void kernel_launch(void* const* d_in, const int* in_sizes, int n_in,
                              void* d_out, int out_size, void* d_ws, size_t ws_size,
                              hipStream_t stream) {
  const float* x      = (const float*)d_in[0];
  const int*   adj    = (const int*)d_in[1];
  const float* w_qkv  = (const float*)d_in[2];
  const float* b_qkv  = (const float*)d_in[3];
  const float* w_proj = (const float*)d_in[4];
  const float* b_proj = (const float*)d_in[5];
  float* out = (float*)d_out;

  char* ws = (char*)d_ws;
  unsigned short* xb  = (unsigned short*)(ws);              // 8.4MB  (reused as yb)
  unsigned short* qb  = (unsigned short*)(ws + 8388608);    // 8.4MB
  unsigned short* kbf = (unsigned short*)(ws + 16777216);   // 8.4MB
  unsigned short* vtb = (unsigned short*)(ws + 25165824);   // 8.4MB
  unsigned short* wqt = (unsigned short*)(ws + 33554432);   // 1.57MB
  unsigned short* wpt = (unsigned short*)(ws + 35127296);   // 0.52MB
  unsigned long long* mb = (unsigned long long*)(ws + 35651584); // 2MB  (end 37.75MB)
  unsigned short* yb = xb;  // x is dead after gemm_qkv

  prep<<<dim3(21504), dim3(256), 0, stream>>>(x, xb, w_qkv, wqt, w_proj, wpt, adj, mb);
  gemm_qkv<<<dim3(64, 12), dim3(256), 0, stream>>>(xb, wqt, b_qkv, qb, kbf, vtb);
  attn<<<dim3(1024), dim3(256), 0, stream>>>(qb, kbf, vtb, mb, yb);
  gemm_proj<<<dim3(64, 4), dim3(256), 0, stream>>>(yb, wpt, b_proj, out);
}